// Round 5
// baseline (329.770 us; speedup 1.0000x reference)
//
#include <hip/hip_runtime.h>
#include <hip/hip_bf16.h>
#include <math.h>

// y[n,o] = min_i (x[n,i] + w[o,i]) + bias[o]
// x: (32768,128) f32, w: (128,128) f32, bias: (128,) f32, out: (32768,128) f32
//
// Round-2 LDS-tiled 4x4 register-blocked structure, with:
//  - K split into two 64-wide phases through ONE 34.8 KB LDS buffer
//    -> 4 blocks/CU (was 2), 4 waves/SIMD -> VALU-issue saturation.
//  - Pad-68 row layout (272 B stride, ≡4 words mod 32 banks) instead of XOR
//    swizzle: same bank behavior (x-reads broadcast, w-reads 2-way=free) but
//    LDS reads become base + compile-time immediate offset (no addr VALU).

constexpr int K   = 128;
constexpr int BM  = 64;
constexpr int BN  = 64;
constexpr int KH  = 64;          // K per phase
constexpr int LDR = KH + 4;      // 68 floats = 272 B row stride

__global__ __launch_bounds__(256, 4)
void minplus_kernel(const float* __restrict__ x,
                    const float* __restrict__ w,
                    const float* __restrict__ bias,
                    float* __restrict__ out)
{
    __shared__ float lds[(BM + BN) * LDR];   // 34,816 B -> 4 blocks/CU
    float* xs = lds;
    float* ws = lds + BM * LDR;

    const int tid = threadIdx.x;
    const int rt  = blockIdx.x & 511;        // ct in HIGH bit: the two col-halves
    const int ct  = blockIdx.x >> 9;         // of a row-tile map to the same XCD

    const float* xsrc = x + (size_t)rt * BM * K;
    const float* wsrc = w + (size_t)ct * BN * K;

    const int ty = tid >> 4;                 // 0..15
    const int tx = tid & 15;                 // 0..15
    const float* xb[4];
    const float* wb[4];
    #pragma unroll
    for (int m = 0; m < 4; ++m) xb[m] = xs + (ty + 16 * m) * LDR;
    #pragma unroll
    for (int n = 0; n < 4; ++n) wb[n] = ws + (tx + 16 * n) * LDR;

    float acc[4][4];
    #pragma unroll
    for (int m = 0; m < 4; ++m)
        #pragma unroll
        for (int n = 0; n < 4; ++n)
            acc[m][n] = INFINITY;

    #pragma unroll
    for (int ph = 0; ph < 2; ++ph) {
        if (ph) __syncthreads();             // compute(ph-1) done before overwrite
        const int k0 = ph * KH;
        // ---- stage 64x64 halves of x and w, coalesced, padded layout ----
        #pragma unroll
        for (int p = 0; p < 4; ++p) {
            int c   = p * 256 + tid;         // 16B chunk id, 0..1023
            int row = c >> 4;                // 0..63
            int kq  = c & 15;                // 16B chunk within 64-float row
            float4 xv = *(const float4*)(xsrc + row * K + k0 + kq * 4);
            float4 wv = *(const float4*)(wsrc + row * K + k0 + kq * 4);
            *(float4*)(xs + row * LDR + kq * 4) = xv;
            *(float4*)(ws + row * LDR + kq * 4) = wv;
        }
        __syncthreads();

        // ---- 16 k-quads, all LDS reads at compile-time immediate offsets ----
        #pragma unroll
        for (int kq = 0; kq < 16; ++kq) {
            float4 xv[4], wv[4];
            #pragma unroll
            for (int m = 0; m < 4; ++m)
                xv[m] = *(const float4*)(xb[m] + kq * 4);
            #pragma unroll
            for (int n = 0; n < 4; ++n)
                wv[n] = *(const float4*)(wb[n] + kq * 4);
            #pragma unroll
            for (int m = 0; m < 4; ++m)
                #pragma unroll
                for (int n = 0; n < 4; ++n) {
                    float a = acc[m][n];
                    // fminf(fminf(a,b),c) -> v_min3_f32
                    a = fminf(fminf(a, xv[m].x + wv[n].x), xv[m].y + wv[n].y);
                    a = fminf(fminf(a, xv[m].z + wv[n].z), xv[m].w + wv[n].w);
                    acc[m][n] = a;
                }
        }
    }

    // ---- epilogue: bias + coalesced-ish store (4 rows x 64B segments) ----
    const int rowbase = rt * BM + ty;
    const int colbase = ct * BN + tx;
    #pragma unroll
    for (int n = 0; n < 4; ++n) {
        float b = bias[colbase + 16 * n];
        #pragma unroll
        for (int m = 0; m < 4; ++m)
            out[(size_t)(rowbase + 16 * m) * 128 + colbase + 16 * n] = acc[m][n] + b;
    }
}

extern "C" void kernel_launch(void* const* d_in, const int* in_sizes, int n_in,
                              void* d_out, int out_size, void* d_ws, size_t ws_size,
                              hipStream_t stream) {
    const float* x    = (const float*)d_in[0];
    const float* w    = (const float*)d_in[1];
    const float* bias = (const float*)d_in[2];
    float* out = (float*)d_out;

    int nrows  = in_sizes[0] / K;             // 32768
    int blocks = (nrows / BM) * (K / BN);     // 1024
    minplus_kernel<<<blocks, 256, 0, stream>>>(x, w, bias, out);
}

// Round 6
// 26.874 us; speedup vs baseline: 12.2711x; 12.2711x over previous
//
#include <hip/hip_runtime.h>
#include <hip/hip_bf16.h>
#include <math.h>

// y[n,o] = min_i (x[n,i] + w[o,i]) + bias[o]
// x: (32768,128) f32, w: (128,128) f32, bias: (128,) f32, out: (32768,128) f32
//
// Round-2 structure (LDS-tiled, 4x4 register block) + round-5 occupancy plan
// (two 64-wide K phases through one 34.8 KB pad-68 LDS buffer -> 4 blocks/CU),
// with the round-5 codegen bug fixed: NO pointer arrays — every LDS access is
// one base pointer + compile-time immediate offset (round-2-proven pattern).
// Phase-1 global loads are issued into named registers before the first
// barrier (T14) so HBM latency hides under phase-0 compute.

constexpr int K   = 128;
constexpr int BM  = 64;
constexpr int BN  = 64;
constexpr int KH  = 64;          // K per phase
constexpr int LDR = KH + 4;      // 68 floats = 272 B row stride (16B-aligned)

__global__ __launch_bounds__(256, 4)
void minplus_kernel(const float* __restrict__ x,
                    const float* __restrict__ w,
                    const float* __restrict__ bias,
                    float* __restrict__ out)
{
    __shared__ float lds[(BM + BN) * LDR];   // 34,816 B -> 4 blocks/CU
    float* xs = lds;
    float* ws = lds + BM * LDR;

    const int tid = threadIdx.x;
    const int rt  = blockIdx.x & 511;        // ct in HIGH bit: both col-halves of
    const int ct  = blockIdx.x >> 9;         // a row-tile share an XCD L2

    const int ty = tid >> 4;                 // 0..15
    const int tx = tid & 15;                 // 0..15

    const float* xsrc = x + (size_t)rt * BM * K;
    const float* wsrc = w + (size_t)ct * BN * K;

    // Staging map: thread stages rows {ty+16p}, 16B-chunk tx, p=0..3.
    // Global float4 index: row*32 + phase*16 + tx. LDS: row*LDR + tx*4.
    const float4* xg = (const float4*)xsrc + ty * 32 + tx;
    const float4* wg = (const float4*)wsrc + ty * 32 + tx;
    float* xd = xs + ty * LDR + tx * 4;
    float* wd = ws + ty * LDR + tx * 4;

    // ---- phase 0 stage (k 0..63) ----
    {
        float4 a0 = xg[0 * 512], a1 = xg[1 * 512], a2 = xg[2 * 512], a3 = xg[3 * 512];
        float4 b0 = wg[0 * 512], b1 = wg[1 * 512], b2 = wg[2 * 512], b3 = wg[3 * 512];
        *(float4*)(xd + 0 * 16 * LDR) = a0;
        *(float4*)(xd + 1 * 16 * LDR) = a1;
        *(float4*)(xd + 2 * 16 * LDR) = a2;
        *(float4*)(xd + 3 * 16 * LDR) = a3;
        *(float4*)(wd + 0 * 16 * LDR) = b0;
        *(float4*)(wd + 1 * 16 * LDR) = b1;
        *(float4*)(wd + 2 * 16 * LDR) = b2;
        *(float4*)(wd + 3 * 16 * LDR) = b3;
    }

    // ---- issue phase-1 global loads NOW (named regs; ds_write after compute0) ----
    float4 px0 = xg[0 * 512 + 16], px1 = xg[1 * 512 + 16],
           px2 = xg[2 * 512 + 16], px3 = xg[3 * 512 + 16];
    float4 pw0 = wg[0 * 512 + 16], pw1 = wg[1 * 512 + 16],
           pw2 = wg[2 * 512 + 16], pw3 = wg[3 * 512 + 16];

    __syncthreads();

    float acc[4][4];
    #pragma unroll
    for (int m = 0; m < 4; ++m)
        #pragma unroll
        for (int n = 0; n < 4; ++n)
            acc[m][n] = INFINITY;

    const float* xbase = xs + ty * LDR;      // compute: thread rows ty+16m
    const float* wbase = ws + tx * LDR;      // compute: thread cols tx+16n

    auto compute = [&]() {
        #pragma unroll
        for (int kq = 0; kq < 16; ++kq) {
            float4 xv[4], wv[4];
            #pragma unroll
            for (int m = 0; m < 4; ++m)
                xv[m] = *(const float4*)(xbase + m * 16 * LDR + kq * 4);
            #pragma unroll
            for (int n = 0; n < 4; ++n)
                wv[n] = *(const float4*)(wbase + n * 16 * LDR + kq * 4);
            #pragma unroll
            for (int m = 0; m < 4; ++m)
                #pragma unroll
                for (int n = 0; n < 4; ++n) {
                    float a = acc[m][n];
                    // fminf(fminf(a,b),c) -> v_min3_f32
                    a = fminf(fminf(a, xv[m].x + wv[n].x), xv[m].y + wv[n].y);
                    a = fminf(fminf(a, xv[m].z + wv[n].z), xv[m].w + wv[n].w);
                    acc[m][n] = a;
                }
        }
    };

    compute();                               // phase 0

    __syncthreads();                         // everyone done reading phase-0 LDS

    // ---- phase 1 stage from prefetched regs ----
    *(float4*)(xd + 0 * 16 * LDR) = px0;
    *(float4*)(xd + 1 * 16 * LDR) = px1;
    *(float4*)(xd + 2 * 16 * LDR) = px2;
    *(float4*)(xd + 3 * 16 * LDR) = px3;
    *(float4*)(wd + 0 * 16 * LDR) = pw0;
    *(float4*)(wd + 1 * 16 * LDR) = pw1;
    *(float4*)(wd + 2 * 16 * LDR) = pw2;
    *(float4*)(wd + 3 * 16 * LDR) = pw3;

    __syncthreads();

    compute();                               // phase 1

    // ---- epilogue: bias + store ----
    const int rowbase = rt * BM + ty;
    const int colbase = ct * BN + tx;
    #pragma unroll
    for (int n = 0; n < 4; ++n) {
        float b = bias[colbase + 16 * n];
        #pragma unroll
        for (int m = 0; m < 4; ++m)
            out[(size_t)(rowbase + 16 * m) * 128 + colbase + 16 * n] = acc[m][n] + b;
    }
}

extern "C" void kernel_launch(void* const* d_in, const int* in_sizes, int n_in,
                              void* d_out, int out_size, void* d_ws, size_t ws_size,
                              hipStream_t stream) {
    const float* x    = (const float*)d_in[0];
    const float* w    = (const float*)d_in[1];
    const float* bias = (const float*)d_in[2];
    float* out = (float*)d_out;

    int nrows  = in_sizes[0] / K;             // 32768
    int blocks = (nrows / BM) * (K / BN);     // 1024
    minplus_kernel<<<blocks, 256, 0, stream>>>(x, w, bias, out);
}